// Round 1
// baseline (570.655 us; speedup 1.0000x reference)
//
#include <hip/hip_runtime.h>
#include <hip/hip_bf16.h>

#define DEV __device__ __forceinline__

typedef unsigned short u16;
typedef unsigned int u32;
typedef __attribute__((ext_vector_type(4))) float f32x4;
typedef __attribute__((ext_vector_type(8))) __bf16 bf16x8;
typedef __attribute__((ext_vector_type(8))) u16 u16x8;
typedef __attribute__((ext_vector_type(4))) u16 u16x4;

DEV u16 f2bf(float f) {
    u32 u = __builtin_bit_cast(u32, f);
    u32 r = (u + 0x7fffu + ((u >> 16) & 1u)) >> 16;
    return (u16)r;
}

DEV void gload_lds16(const void* g, void* l) {
    void* gg = const_cast<void*>(g);
    __builtin_amdgcn_global_load_lds(
        (const __attribute__((address_space(1))) void*)gg,
        (__attribute__((address_space(3))) void*)l,
        16, 0, 0);
}

// ---------------- f32 -> bf16 conversion ----------------
__global__ void cvt_f32_bf16(const float* __restrict__ in, u16* __restrict__ out, int n4) {
    int i = blockIdx.x * blockDim.x + threadIdx.x;
    if (i < n4) {
        float4 v = ((const float4*)in)[i];
        u16x4 o;
        o[0] = f2bf(v.x); o[1] = f2bf(v.y); o[2] = f2bf(v.z); o[3] = f2bf(v.w);
        ((u16x4*)out)[i] = o;
    }
}

// ---------------- GEMM: C[M,N] = A[M,K] * B[N,K]^T + bias ----------------
// A, B bf16 row-major (K contiguous). 128x128 tile, BK=64, 4 waves (2x2 of 64x64).
template<int F32OUT>
__global__ __launch_bounds__(256) void gemm_bt(
    const u16* __restrict__ A, const u16* __restrict__ B,
    const float* __restrict__ bias, void* __restrict__ Cv,
    int M, int N, int K)
{
    __shared__ u16 As[128 * 64];
    __shared__ u16 Bs[128 * 64];
    const int t = threadIdx.x;
    const int lane = t & 63;
    const int w = t >> 6;
    const int wm = w >> 1, wn = w & 1;
    const int bm = blockIdx.y * 128, bn = blockIdx.x * 128;
    const int lr = lane & 15;   // frag row/col
    const int lg = lane >> 4;   // k-group 0..3

    f32x4 acc[4][4] = {};

    for (int k0 = 0; k0 < K; k0 += 64) {
        #pragma unroll
        for (int i = 0; i < 4; ++i) {
            int off = (t + i * 256) * 16;   // byte offset within 128x64(bf16) tile
            int row = off >> 7;             // 0..127
            int colb = off & 127;           // byte within row
            gload_lds16((const char*)A + ((size_t)(bm + row) * K + k0) * 2 + colb,
                        (char*)As + off);
            gload_lds16((const char*)B + ((size_t)(bn + row) * K + k0) * 2 + colb,
                        (char*)Bs + off);
        }
        __syncthreads();
        #pragma unroll
        for (int kk = 0; kk < 2; ++kk) {
            bf16x8 af[4], bfr[4];
            #pragma unroll
            for (int m = 0; m < 4; ++m)
                af[m] = *(const bf16x8*)&As[(wm * 64 + m * 16 + lr) * 64 + kk * 32 + lg * 8];
            #pragma unroll
            for (int n = 0; n < 4; ++n)
                bfr[n] = *(const bf16x8*)&Bs[(wn * 64 + n * 16 + lr) * 64 + kk * 32 + lg * 8];
            #pragma unroll
            for (int m = 0; m < 4; ++m)
                #pragma unroll
                for (int n = 0; n < 4; ++n)
                    acc[m][n] = __builtin_amdgcn_mfma_f32_16x16x32_bf16(af[m], bfr[n], acc[m][n], 0, 0, 0);
        }
        __syncthreads();
    }

    // epilogue: C/D layout col = lane&15, row = (lane>>4)*4 + r
    #pragma unroll
    for (int n = 0; n < 4; ++n) {
        int col = bn + wn * 64 + n * 16 + lr;
        float bv = bias[col];
        #pragma unroll
        for (int m = 0; m < 4; ++m) {
            int row0 = bm + wm * 64 + m * 16 + lg * 4;
            #pragma unroll
            for (int r = 0; r < 4; ++r) {
                float v = acc[m][n][r] + bv;
                size_t idx = (size_t)(row0 + r) * N + col;
                if (F32OUT) ((float*)Cv)[idx] = v;
                else        ((u16*)Cv)[idx] = f2bf(v);
            }
        }
    }
}

// ---------------- causal flash attention ----------------
// Q,K,V,O: bf16 flat [B*T, D], head h at cols h*64..h*64+63.
// Block: 4 waves, 64 q-rows (16 per wave). KV tile = 32 rows.
__global__ __launch_bounds__(256) void attn_fwd(
    const u16* __restrict__ Qm, const u16* __restrict__ Km, const u16* __restrict__ Vm,
    u16* __restrict__ Om)
{
    constexpr int T = 2048, D = 1024;
    __shared__ u16 Ks[32 * 64];
    __shared__ u16 Vt[64 * 32];
    __shared__ u16 Ps[4][16 * 32];

    const int t = threadIdx.x, lane = t & 63, w = t >> 6;
    const int lr = lane & 15, lg = lane >> 4;
    const int bh = blockIdx.y, b = bh >> 4, h = bh & 15;
    const int q0 = blockIdx.x * 64;
    const size_t headoff = (size_t)b * T * D + h * 64;

    // Q fragments for this wave's 16 rows (k = dk dimension, 64 wide -> 2 frags)
    bf16x8 qf[2];
    {
        const u16* qp = Qm + headoff + (size_t)(q0 + w * 16 + lr) * D + lg * 8;
        qf[0] = *(const bf16x8*)(qp);
        qf[1] = *(const bf16x8*)(qp + 32);
    }

    f32x4 o_acc[4] = {};
    float mrow[4] = { -__builtin_inff(), -__builtin_inff(), -__builtin_inff(), -__builtin_inff() };
    float lrow[4] = {};

    const int kv_end = q0 + 64;
    for (int kv0 = 0; kv0 < kv_end; kv0 += 32) {
        // stage K tile [32][64] via global_load_lds (4096 B = 256 thr * 16 B)
        {
            int off = t * 16;
            int row = off >> 7, colb = off & 127;
            gload_lds16((const char*)Km + (headoff + (size_t)(kv0 + row) * D) * 2 + colb,
                        (char*)Ks + off);
        }
        // stage V transposed: Vt[dk][kv] = V[kv0+kv][dk]
        {
            int kv = t >> 3, d0 = (t & 7) * 8;
            u16x8 vv = *(const u16x8*)(Vm + headoff + (size_t)(kv0 + kv) * D + d0);
            #pragma unroll
            for (int j = 0; j < 8; ++j)
                Vt[(d0 + j) * 32 + kv] = vv[j];
        }
        __syncthreads();

        // S = Q K^T : two 16x16 kv-column tiles
        f32x4 s[2] = {};
        #pragma unroll
        for (int kk = 0; kk < 2; ++kk) {
            #pragma unroll
            for (int n = 0; n < 2; ++n) {
                bf16x8 kf = *(const bf16x8*)&Ks[(n * 16 + lr) * 64 + kk * 32 + lg * 8];
                s[n] = __builtin_amdgcn_mfma_f32_16x16x32_bf16(qf[kk], kf, s[n], 0, 0, 0);
            }
        }

        // online softmax, rows owned by (lg, r)
        const int qrow_base = q0 + w * 16 + lg * 4;
        #pragma unroll
        for (int r = 0; r < 4; ++r) {
            int qg = qrow_base + r;
            float a0 = s[0][r] * 0.125f;
            float a1 = s[1][r] * 0.125f;
            if (kv0 + lr > qg)      a0 = -__builtin_inff();
            if (kv0 + 16 + lr > qg) a1 = -__builtin_inff();
            float mx = fmaxf(a0, a1);
            mx = fmaxf(mx, __shfl_xor(mx, 1));
            mx = fmaxf(mx, __shfl_xor(mx, 2));
            mx = fmaxf(mx, __shfl_xor(mx, 4));
            mx = fmaxf(mx, __shfl_xor(mx, 8));
            float mn = fmaxf(mrow[r], mx);
            float p0 = __expf(a0 - mn);
            float p1 = __expf(a1 - mn);
            float corr = __expf(mrow[r] - mn);
            mrow[r] = mn;
            float sum = p0 + p1;
            sum += __shfl_xor(sum, 1);
            sum += __shfl_xor(sum, 2);
            sum += __shfl_xor(sum, 4);
            sum += __shfl_xor(sum, 8);
            lrow[r] = lrow[r] * corr + sum;
            #pragma unroll
            for (int d = 0; d < 4; ++d) o_acc[d][r] *= corr;
            Ps[w][(lg * 4 + r) * 32 + lr]      = f2bf(p0);
            Ps[w][(lg * 4 + r) * 32 + 16 + lr] = f2bf(p1);
        }

        // O += P V  (P: A-operand layout read back from LDS)
        bf16x8 pf = *(const bf16x8*)&Ps[w][lr * 32 + lg * 8];
        #pragma unroll
        for (int d = 0; d < 4; ++d) {
            bf16x8 vf = *(const bf16x8*)&Vt[(d * 16 + lr) * 32 + lg * 8];
            o_acc[d] = __builtin_amdgcn_mfma_f32_16x16x32_bf16(pf, vf, o_acc[d], 0, 0, 0);
        }
        __syncthreads();
    }

    // epilogue: O / l
    #pragma unroll
    for (int d = 0; d < 4; ++d) {
        #pragma unroll
        for (int r = 0; r < 4; ++r) {
            float v = o_acc[d][r] / lrow[r];
            Om[headoff + (size_t)(q0 + w * 16 + lg * 4 + r) * D + d * 16 + lr] = f2bf(v);
        }
    }
}

extern "C" void kernel_launch(void* const* d_in, const int* in_sizes, int n_in,
                              void* d_out, int out_size, void* d_ws, size_t ws_size,
                              hipStream_t stream)
{
    const float* x  = (const float*)d_in[0];
    const float* Wq = (const float*)d_in[1];
    const float* bq = (const float*)d_in[2];
    const float* Wk = (const float*)d_in[3];
    const float* bk = (const float*)d_in[4];
    const float* Wv = (const float*)d_in[5];
    const float* bv = (const float*)d_in[6];
    const float* Wo = (const float*)d_in[7];
    const float* bo = (const float*)d_in[8];

    constexpr int B = 4, T = 2048, D = 1024;
    constexpr size_t MT = (size_t)B * T;   // 8192

    const size_t NEED = (size_t)88 << 20;
    if (ws_size < NEED) return;   // fail loudly (output stays poisoned)

    char* ws = (char*)d_ws;
    u16* xb  = (u16*)(ws);
    u16* Wqb = (u16*)(ws + ((size_t)16 << 20));
    u16* Wkb = (u16*)(ws + ((size_t)18 << 20));
    u16* Wvb = (u16*)(ws + ((size_t)20 << 20));
    u16* Wob = (u16*)(ws + ((size_t)22 << 20));
    u16* Qb  = (u16*)(ws + ((size_t)24 << 20));
    u16* Kb  = (u16*)(ws + ((size_t)40 << 20));
    u16* Vb  = (u16*)(ws + ((size_t)56 << 20));
    u16* Ob  = (u16*)(ws + ((size_t)72 << 20));

    int nx4 = (int)(MT * D / 4);
    cvt_f32_bf16<<<(nx4 + 255) / 256, 256, 0, stream>>>(x, xb, nx4);
    int nw4 = D * D / 4;
    cvt_f32_bf16<<<(nw4 + 255) / 256, 256, 0, stream>>>(Wq, Wqb, nw4);
    cvt_f32_bf16<<<(nw4 + 255) / 256, 256, 0, stream>>>(Wk, Wkb, nw4);
    cvt_f32_bf16<<<(nw4 + 255) / 256, 256, 0, stream>>>(Wv, Wvb, nw4);
    cvt_f32_bf16<<<(nw4 + 255) / 256, 256, 0, stream>>>(Wo, Wob, nw4);

    dim3 gg(D / 128, MT / 128);   // (8, 64)
    gemm_bt<0><<<gg, 256, 0, stream>>>(xb, Wqb, bq, Qb, (int)MT, D, D);
    gemm_bt<0><<<gg, 256, 0, stream>>>(xb, Wkb, bk, Kb, (int)MT, D, D);
    gemm_bt<0><<<gg, 256, 0, stream>>>(xb, Wvb, bv, Vb, (int)MT, D, D);

    attn_fwd<<<dim3(T / 64, B * 16), 256, 0, stream>>>(Qb, Kb, Vb, Ob);

    gemm_bt<1><<<gg, 256, 0, stream>>>(Ob, Wob, bo, d_out, (int)MT, D, D);
}

// Round 2
// 378.563 us; speedup vs baseline: 1.5074x; 1.5074x over previous
//
#include <hip/hip_runtime.h>
#include <hip/hip_bf16.h>

#define DEV __device__ __forceinline__

typedef unsigned short u16;
typedef unsigned int u32;
typedef __attribute__((ext_vector_type(4))) float f32x4;
typedef __attribute__((ext_vector_type(8))) __bf16 bf16x8;
typedef __attribute__((ext_vector_type(8))) u16 u16x8;
typedef __attribute__((ext_vector_type(4))) u16 u16x4;

DEV u16 f2bf(float f) {
    u32 u = __builtin_bit_cast(u32, f);
    u32 r = (u + 0x7fffu + ((u >> 16) & 1u)) >> 16;
    return (u16)r;
}

// round-to-nearest for known non-NaN, non-negative-inf values (P, O)
DEV u16 f2bf_fast(float f) {
    u32 u = __builtin_bit_cast(u32, f);
    return (u16)((u + 0x8000u) >> 16);
}

DEV float fastrcp(float x) {
#if __has_builtin(__builtin_amdgcn_rcpf)
    return __builtin_amdgcn_rcpf(x);
#else
    return 1.0f / x;
#endif
}

DEV void gload_lds16(const void* g, void* l) {
    void* gg = const_cast<void*>(g);
    __builtin_amdgcn_global_load_lds(
        (const __attribute__((address_space(1))) void*)gg,
        (__attribute__((address_space(3))) void*)l,
        16, 0, 0);
}

// ---------------- f32 -> bf16 conversion ----------------
__global__ void cvt_f32_bf16(const float* __restrict__ in, u16* __restrict__ out, int n4) {
    int i = blockIdx.x * blockDim.x + threadIdx.x;
    if (i < n4) {
        float4 v = ((const float4*)in)[i];
        u16x4 o;
        o[0] = f2bf(v.x); o[1] = f2bf(v.y); o[2] = f2bf(v.z); o[3] = f2bf(v.w);
        ((u16x4*)out)[i] = o;
    }
}

// ---------------- GEMM: C[M,N] = A[M,K] * B[N,K]^T + bias ----------------
template<int F32OUT>
__global__ __launch_bounds__(256) void gemm_bt(
    const u16* __restrict__ A, const u16* __restrict__ B,
    const float* __restrict__ bias, void* __restrict__ Cv,
    int M, int N, int K)
{
    __shared__ u16 As[128 * 64];
    __shared__ u16 Bs[128 * 64];
    const int t = threadIdx.x;
    const int lane = t & 63;
    const int w = t >> 6;
    const int wm = w >> 1, wn = w & 1;
    const int bm = blockIdx.y * 128, bn = blockIdx.x * 128;
    const int lr = lane & 15;
    const int lg = lane >> 4;

    f32x4 acc[4][4] = {};

    for (int k0 = 0; k0 < K; k0 += 64) {
        #pragma unroll
        for (int i = 0; i < 4; ++i) {
            int off = (t + i * 256) * 16;
            int row = off >> 7;
            int colb = off & 127;
            gload_lds16((const char*)A + ((size_t)(bm + row) * K + k0) * 2 + colb,
                        (char*)As + off);
            gload_lds16((const char*)B + ((size_t)(bn + row) * K + k0) * 2 + colb,
                        (char*)Bs + off);
        }
        __syncthreads();
        #pragma unroll
        for (int kk = 0; kk < 2; ++kk) {
            bf16x8 af[4], bfr[4];
            #pragma unroll
            for (int m = 0; m < 4; ++m)
                af[m] = *(const bf16x8*)&As[(wm * 64 + m * 16 + lr) * 64 + kk * 32 + lg * 8];
            #pragma unroll
            for (int n = 0; n < 4; ++n)
                bfr[n] = *(const bf16x8*)&Bs[(wn * 64 + n * 16 + lr) * 64 + kk * 32 + lg * 8];
            #pragma unroll
            for (int m = 0; m < 4; ++m)
                #pragma unroll
                for (int n = 0; n < 4; ++n)
                    acc[m][n] = __builtin_amdgcn_mfma_f32_16x16x32_bf16(af[m], bfr[n], acc[m][n], 0, 0, 0);
        }
        __syncthreads();
    }

    #pragma unroll
    for (int n = 0; n < 4; ++n) {
        int col = bn + wn * 64 + n * 16 + lr;
        float bv = bias[col];
        #pragma unroll
        for (int m = 0; m < 4; ++m) {
            int row0 = bm + wm * 64 + m * 16 + lg * 4;
            #pragma unroll
            for (int r = 0; r < 4; ++r) {
                float v = acc[m][n][r] + bv;
                size_t idx = (size_t)(row0 + r) * N + col;
                if (F32OUT) ((float*)Cv)[idx] = v;
                else        ((u16*)Cv)[idx] = f2bf(v);
            }
        }
    }
}

// ---------------- causal flash attention, v2 ----------------
// Q,K,V,O: bf16 flat [B*T, D], head h at cols h*64..h*64+63.
// Block: 4 waves; QBLK = 128 rows. Wave w owns rows {w*16..} and {64+w*16..}.
// KVBLK = 64, double-buffered. K: global_load_lds w/ XOR-swizzled source.
// V: transposed to Vt[dk][kv], stride 72. P: per-wave LDS, stride 72.
__global__ __launch_bounds__(256) void attn_fwd(
    const u16* __restrict__ Qm, const u16* __restrict__ Km, const u16* __restrict__ Vm,
    u16* __restrict__ Om)
{
    constexpr int T = 2048, D = 1024;
    constexpr float SCALE = 0.125f;   // 1/sqrt(64)
    constexpr int PSTR = 72;          // padded kv stride (u16 elems)

    __shared__ u16 Ks[2][64 * 64];    // row stride 64 elems, XOR-swizzled content
    __shared__ u16 Vt[2][64 * PSTR];  // Vt[dk][kv]
    __shared__ u16 Ps[4][32 * PSTR];  // per-wave P, rows: m*16 + lr

    const int t = threadIdx.x, lane = t & 63, w = t >> 6;
    const int lr = lane & 15, lg = lane >> 4;
    const int bh = blockIdx.y, b = bh >> 4, h = bh & 15;
    const int q0 = ((int)gridDim.x - 1 - (int)blockIdx.x) * 128;  // heavy blocks first
    const size_t headoff = (size_t)b * T * D + h * 64;
    const int nt = q0 / 64 + 2;

    // ---- Q fragments in registers (2 m-tiles x 2 kk) ----
    int qrow[2];
    qrow[0] = q0 + w * 16;
    qrow[1] = q0 + 64 + w * 16;
    bf16x8 qf[2][2];
    #pragma unroll
    for (int m = 0; m < 2; ++m) {
        const u16* qp = Qm + headoff + (size_t)(qrow[m] + lr) * D + lg * 8;
        qf[m][0] = *(const bf16x8*)qp;
        qf[m][1] = *(const bf16x8*)(qp + 32);
    }

    f32x4 o_acc[2][4] = {};
    float mrow[2][4], lrow[2][4];
    #pragma unroll
    for (int m = 0; m < 2; ++m)
        #pragma unroll
        for (int r = 0; r < 4; ++r) { mrow[m][r] = -__builtin_inff(); lrow[m][r] = 0.f; }

    // ---- staging helpers ----
    // K tile [64 rows][64 dk], content XOR-swizzled: LDS elem (row, c') holds
    // K[row][c' ^ 8*(row&7)] -> read col c at c' = c ^ 8*(row&7).
    auto stageK = [&](int buf, int kv0) {
        #pragma unroll
        for (int i = 0; i < 2; ++i) {
            int idx = t + i * 256;          // 0..511, 16B each
            int row = idx >> 3, slot = idx & 7;
            gload_lds16(Km + headoff + (size_t)(kv0 + row) * D + 8 * (slot ^ (row & 7)),
                        (char*)Ks[buf] + idx * 16);
        }
    };
    u16x8 vv0, vv1;
    auto loadV = [&](int kv0) {
        int kv = t & 63, d0 = (t >> 6) * 8;
        const u16* vp = Vm + headoff + (size_t)(kv0 + kv) * D + d0;
        vv0 = *(const u16x8*)vp;
        vv1 = *(const u16x8*)(vp + 32);
    };
    auto writeVt = [&](int buf) {
        int kv = t & 63, d0 = (t >> 6) * 8;
        #pragma unroll
        for (int j = 0; j < 8; ++j) {
            Vt[buf][(d0 + j) * PSTR + kv]      = vv0[j];
            Vt[buf][(d0 + 32 + j) * PSTR + kv] = vv1[j];
        }
    };

    // ---- prologue ----
    stageK(0, 0);
    loadV(0);
    writeVt(0);

    int cur = 0;
    for (int it = 0; it < nt; ++it) {
        const int kv0 = it * 64;
        __syncthreads();   // staged K (vmcnt) + Vt (lgkm) for buf `cur` ready; prev reads done

        if (it + 1 < nt) {
            stageK(cur ^ 1, kv0 + 64);
            loadV(kv0 + 64);
        }

        const bool act0 = (kv0 <= qrow[0] + 15);   // m=1 is always active

        // ---- QK^T ----
        f32x4 sacc[2][4] = {};
        #pragma unroll
        for (int kk = 0; kk < 2; ++kk) {
            #pragma unroll
            for (int n = 0; n < 4; ++n) {
                int row = n * 16 + lr;
                const bf16x8 kf = *(const bf16x8*)((const char*)Ks[cur] + row * 128 +
                                    ((kk * 64 + lg * 16) ^ ((lr & 7) << 4)));
                #pragma unroll
                for (int m = 0; m < 2; ++m) {
                    if (m == 0 && !act0) continue;
                    sacc[m][n] = __builtin_amdgcn_mfma_f32_16x16x32_bf16(qf[m][kk], kf, sacc[m][n], 0, 0, 0);
                }
            }
        }

        // ---- online softmax (per m-tile), P -> LDS ----
        #pragma unroll
        for (int m = 0; m < 2; ++m) {
            if (m == 0 && !act0) continue;
            const bool needmask = (kv0 + 63 > qrow[m]);
            float a[4][4];
            #pragma unroll
            for (int n = 0; n < 4; ++n)
                #pragma unroll
                for (int r = 0; r < 4; ++r) {
                    float v = sacc[m][n][r] * SCALE;
                    if (needmask && (kv0 + n * 16 + lr > qrow[m] + lg * 4 + r))
                        v = -__builtin_inff();
                    a[n][r] = v;
                }

            float pm[4];
            #pragma unroll
            for (int r = 0; r < 4; ++r) {
                pm[r] = fmaxf(fmaxf(a[0][r], a[1][r]), fmaxf(a[2][r], a[3][r]));
                pm[r] = fmaxf(pm[r], __shfl_xor(pm[r], 1));
                pm[r] = fmaxf(pm[r], __shfl_xor(pm[r], 2));
                pm[r] = fmaxf(pm[r], __shfl_xor(pm[r], 4));
                pm[r] = fmaxf(pm[r], __shfl_xor(pm[r], 8));
            }

            // defer-max (T13): rescale only if some row max grew past THR=8
            float dm = fmaxf(fmaxf(pm[0] - mrow[m][0], pm[1] - mrow[m][1]),
                             fmaxf(pm[2] - mrow[m][2], pm[3] - mrow[m][3]));
            if (__any(dm > 8.0f)) {
                #pragma unroll
                for (int r = 0; r < 4; ++r) {
                    float mn = fmaxf(mrow[m][r], pm[r]);
                    float corr = __expf(mrow[m][r] - mn);
                    mrow[m][r] = mn;
                    lrow[m][r] *= corr;
                    #pragma unroll
                    for (int n = 0; n < 4; ++n) o_acc[m][n][r] *= corr;
                }
            }

            float rs[4];
            #pragma unroll
            for (int r = 0; r < 4; ++r) rs[r] = 0.f;
            #pragma unroll
            for (int n = 0; n < 4; ++n) {
                #pragma unroll
                for (int r = 0; r < 4; ++r) {
                    float p = __expf(a[n][r] - mrow[m][r]);
                    rs[r] += p;
                    Ps[w][(m * 16 + lg * 4 + r) * PSTR + n * 16 + lr] = f2bf_fast(p);
                }
            }
            #pragma unroll
            for (int r = 0; r < 4; ++r) {
                rs[r] += __shfl_xor(rs[r], 1);
                rs[r] += __shfl_xor(rs[r], 2);
                rs[r] += __shfl_xor(rs[r], 4);
                rs[r] += __shfl_xor(rs[r], 8);
                lrow[m][r] += rs[r];
            }
        }

        // ---- PV ----
        #pragma unroll
        for (int kk = 0; kk < 2; ++kk) {
            bf16x8 pf[2];
            #pragma unroll
            for (int m = 0; m < 2; ++m) {
                if (m == 0 && !act0) continue;
                pf[m] = *(const bf16x8*)&Ps[w][(m * 16 + lr) * PSTR + kk * 32 + lg * 8];
            }
            #pragma unroll
            for (int n = 0; n < 4; ++n) {
                const bf16x8 vf = *(const bf16x8*)&Vt[cur][(n * 16 + lr) * PSTR + kk * 32 + lg * 8];
                #pragma unroll
                for (int m = 0; m < 2; ++m) {
                    if (m == 0 && !act0) continue;
                    o_acc[m][n] = __builtin_amdgcn_mfma_f32_16x16x32_bf16(pf[m], vf, o_acc[m][n], 0, 0, 0);
                }
            }
        }

        if (it + 1 < nt) writeVt(cur ^ 1);
        cur ^= 1;
    }

    // ---- epilogue ----
    #pragma unroll
    for (int m = 0; m < 2; ++m) {
        #pragma unroll
        for (int r = 0; r < 4; ++r) {
            float inv = fastrcp(lrow[m][r]);
            size_t rowoff = headoff + (size_t)(qrow[m] + lg * 4 + r) * D;
            #pragma unroll
            for (int n = 0; n < 4; ++n) {
                float v = o_acc[m][n][r] * inv;
                Om[rowoff + n * 16 + lr] = f2bf_fast(v);
            }
        }
    }
}

extern "C" void kernel_launch(void* const* d_in, const int* in_sizes, int n_in,
                              void* d_out, int out_size, void* d_ws, size_t ws_size,
                              hipStream_t stream)
{
    const float* x  = (const float*)d_in[0];
    const float* Wq = (const float*)d_in[1];
    const float* bq = (const float*)d_in[2];
    const float* Wk = (const float*)d_in[3];
    const float* bk = (const float*)d_in[4];
    const float* Wv = (const float*)d_in[5];
    const float* bv = (const float*)d_in[6];
    const float* Wo = (const float*)d_in[7];
    const float* bo = (const float*)d_in[8];

    constexpr int B = 4, T = 2048, D = 1024;
    constexpr size_t MT = (size_t)B * T;   // 8192

    const size_t NEED = (size_t)88 << 20;
    if (ws_size < NEED) return;

    char* ws = (char*)d_ws;
    u16* xb  = (u16*)(ws);
    u16* Wqb = (u16*)(ws + ((size_t)16 << 20));
    u16* Wkb = (u16*)(ws + ((size_t)18 << 20));
    u16* Wvb = (u16*)(ws + ((size_t)20 << 20));
    u16* Wob = (u16*)(ws + ((size_t)22 << 20));
    u16* Qb  = (u16*)(ws + ((size_t)24 << 20));
    u16* Kb  = (u16*)(ws + ((size_t)40 << 20));
    u16* Vb  = (u16*)(ws + ((size_t)56 << 20));
    u16* Ob  = (u16*)(ws + ((size_t)72 << 20));

    int nx4 = (int)(MT * D / 4);
    cvt_f32_bf16<<<(nx4 + 255) / 256, 256, 0, stream>>>(x, xb, nx4);
    int nw4 = D * D / 4;
    cvt_f32_bf16<<<(nw4 + 255) / 256, 256, 0, stream>>>(Wq, Wqb, nw4);
    cvt_f32_bf16<<<(nw4 + 255) / 256, 256, 0, stream>>>(Wk, Wkb, nw4);
    cvt_f32_bf16<<<(nw4 + 255) / 256, 256, 0, stream>>>(Wv, Wvb, nw4);
    cvt_f32_bf16<<<(nw4 + 255) / 256, 256, 0, stream>>>(Wo, Wob, nw4);

    dim3 gg(D / 128, MT / 128);   // (8, 64)
    gemm_bt<0><<<gg, 256, 0, stream>>>(xb, Wqb, bq, Qb, (int)MT, D, D);
    gemm_bt<0><<<gg, 256, 0, stream>>>(xb, Wkb, bk, Kb, (int)MT, D, D);
    gemm_bt<0><<<gg, 256, 0, stream>>>(xb, Wvb, bv, Vb, (int)MT, D, D);

    attn_fwd<<<dim3(T / 128, B * 16), 256, 0, stream>>>(Qb, Kb, Vb, Ob);

    gemm_bt<1><<<gg, 256, 0, stream>>>(Ob, Wob, bo, d_out, (int)MT, D, D);
}

// Round 3
// 277.882 us; speedup vs baseline: 2.0536x; 1.3623x over previous
//
#include <hip/hip_runtime.h>
#include <hip/hip_bf16.h>

#define DEV __device__ __forceinline__

typedef unsigned short u16;
typedef unsigned int u32;
typedef __attribute__((ext_vector_type(4))) float f32x4;
typedef __attribute__((ext_vector_type(16))) float f32x16;
typedef __attribute__((ext_vector_type(8))) __bf16 bf16x8;
typedef __attribute__((ext_vector_type(8))) u16 u16x8;
typedef __attribute__((ext_vector_type(4))) u16 u16x4;
typedef __attribute__((ext_vector_type(4))) u32 u32x4;

DEV u16 f2bf(float f) {
    u32 u = __builtin_bit_cast(u32, f);
    u32 r = (u + 0x7fffu + ((u >> 16) & 1u)) >> 16;
    return (u16)r;
}

DEV u16 f2bf_fast(float f) {
    u32 u = __builtin_bit_cast(u32, f);
    return (u16)((u + 0x8000u) >> 16);
}

DEV float fastrcp(float x) {
#if __has_builtin(__builtin_amdgcn_rcpf)
    return __builtin_amdgcn_rcpf(x);
#else
    return 1.0f / x;
#endif
}

DEV u32 cvtpk_bf16(float lo, float hi) {
    u32 r;
    asm("v_cvt_pk_bf16_f32 %0, %1, %2" : "=v"(r) : "v"(lo), "v"(hi));
    return r;
}

DEV void plswap(u32& a, u32& b) {
    asm volatile("v_permlane32_swap_b32 %0, %1" : "+v"(a), "+v"(b));
}

DEV void gload_lds16(const void* g, void* l) {
    void* gg = const_cast<void*>(g);
    __builtin_amdgcn_global_load_lds(
        (const __attribute__((address_space(1))) void*)gg,
        (__attribute__((address_space(3))) void*)l,
        16, 0, 0);
}

DEV f32x16 mfma32(bf16x8 a, bf16x8 b, f32x16 c) {
    return __builtin_amdgcn_mfma_f32_32x32x16_bf16(a, b, c, 0, 0, 0);
}

// ---------------- f32 -> bf16 conversion ----------------
__global__ void cvt_f32_bf16(const float* __restrict__ in, u16* __restrict__ out, int n4) {
    int i = blockIdx.x * blockDim.x + threadIdx.x;
    if (i < n4) {
        float4 v = ((const float4*)in)[i];
        u16x4 o;
        o[0] = f2bf(v.x); o[1] = f2bf(v.y); o[2] = f2bf(v.z); o[3] = f2bf(v.w);
        ((u16x4*)out)[i] = o;
    }
}

// ---------------- GEMM: C[M,N] = A[M,K] * B[N,K]^T + bias ----------------
template<int F32OUT>
__global__ __launch_bounds__(256) void gemm_bt(
    const u16* __restrict__ A, const u16* __restrict__ B,
    const float* __restrict__ bias, void* __restrict__ Cv,
    int M, int N, int K)
{
    __shared__ u16 As[128 * 64];
    __shared__ u16 Bs[128 * 64];
    const int t = threadIdx.x;
    const int lane = t & 63;
    const int w = t >> 6;
    const int wm = w >> 1, wn = w & 1;
    const int bm = blockIdx.y * 128, bn = blockIdx.x * 128;
    const int lr = lane & 15;
    const int lg = lane >> 4;

    f32x4 acc[4][4] = {};

    for (int k0 = 0; k0 < K; k0 += 64) {
        #pragma unroll
        for (int i = 0; i < 4; ++i) {
            int off = (t + i * 256) * 16;
            int row = off >> 7;
            int colb = off & 127;
            gload_lds16((const char*)A + ((size_t)(bm + row) * K + k0) * 2 + colb,
                        (char*)As + off);
            gload_lds16((const char*)B + ((size_t)(bn + row) * K + k0) * 2 + colb,
                        (char*)Bs + off);
        }
        __syncthreads();
        #pragma unroll
        for (int kk = 0; kk < 2; ++kk) {
            bf16x8 af[4], bfr[4];
            #pragma unroll
            for (int m = 0; m < 4; ++m)
                af[m] = *(const bf16x8*)&As[(wm * 64 + m * 16 + lr) * 64 + kk * 32 + lg * 8];
            #pragma unroll
            for (int n = 0; n < 4; ++n)
                bfr[n] = *(const bf16x8*)&Bs[(wn * 64 + n * 16 + lr) * 64 + kk * 32 + lg * 8];
            #pragma unroll
            for (int m = 0; m < 4; ++m)
                #pragma unroll
                for (int n = 0; n < 4; ++n)
                    acc[m][n] = __builtin_amdgcn_mfma_f32_16x16x32_bf16(af[m], bfr[n], acc[m][n], 0, 0, 0);
        }
        __syncthreads();
    }

    #pragma unroll
    for (int n = 0; n < 4; ++n) {
        int col = bn + wn * 64 + n * 16 + lr;
        float bv = bias[col];
        #pragma unroll
        for (int m = 0; m < 4; ++m) {
            int row0 = bm + wm * 64 + m * 16 + lg * 4;
            #pragma unroll
            for (int r = 0; r < 4; ++r) {
                float v = acc[m][n][r] + bv;
                size_t idx = (size_t)(row0 + r) * N + col;
                if (F32OUT) ((float*)Cv)[idx] = v;
                else        ((u16*)Cv)[idx] = f2bf(v);
            }
        }
    }
}

// ---------------- causal flash attention, v3: swapped QK^T, 32x32 MFMA ----
// Each lane owns one q-row (col = lane&31); softmax fully in-register.
// Block: 4 waves x 32 q-rows = 128. KVBLK = 64, double-buffered.
__global__ __launch_bounds__(256) void attn_fwd(
    const u16* __restrict__ Qm, const u16* __restrict__ Km, const u16* __restrict__ Vm,
    u16* __restrict__ Om)
{
    constexpr int T = 2048, D = 1024;
    constexpr float C = 0.18033688f;      // 0.125 * log2(e)
    constexpr int PSTR = 72;
    constexpr float NEG = -3.0e38f;

    __shared__ __align__(16) u16 Ks[2][64 * 64];     // XOR-swizzled K rows
    __shared__ __align__(16) u16 Vt[2][64 * PSTR];   // Vt[d][kv]

    const int t = threadIdx.x, lane = t & 63, w = t >> 6;
    const int ql = lane & 31, hi = lane >> 5;

    // XCD-aware remap: blocks with id%8==k handle heads k*8..k*8+7 (4MB K+V = one L2)
    const int id = (int)blockIdx.y * 16 + (int)blockIdx.x;
    const int bh = (id & 7) * 8 + ((id >> 3) >> 4);
    const int xb = (id >> 3) & 15;
    const int b = bh >> 4, h = bh & 15;
    const int q0 = (15 - xb) * 128;                  // heavy blocks first
    const size_t headoff = (size_t)b * T * D + h * 64;
    const int nt = q0 / 64 + 2;

    const int qg = q0 + w * 32 + ql;                 // this lane's q row
    const int qmax = q0 + w * 32 + 31;               // wave's last q row

    // ---- Q fragments (pre-loaded, reused every iter) ----
    bf16x8 qf[4];
    {
        const u16* qp = Qm + headoff + (size_t)qg * D + hi * 8;
        #pragma unroll
        for (int s = 0; s < 4; ++s) qf[s] = *(const bf16x8*)(qp + s * 16);
    }

    f32x16 oa[2] = {};
    float m = NEG, l = 0.f;

    // ---- staging ----
    auto stageK = [&](int buf, int kv0) {
        #pragma unroll
        for (int i = 0; i < 2; ++i) {
            int idx = t + i * 256;
            int row = idx >> 3, slot = idx & 7;
            gload_lds16(Km + headoff + (size_t)(kv0 + row) * D + 8 * (slot ^ (row & 7)),
                        (char*)Ks[buf] + idx * 16);
        }
    };
    u16x8 vva, vvb;
    auto loadV = [&](int kv0) {
        int kv = t & 63, d0 = (t >> 6) * 8;
        const u16* vp = Vm + headoff + (size_t)(kv0 + kv) * D + d0;
        vva = *(const u16x8*)vp;
        vvb = *(const u16x8*)(vp + 32);
    };
    auto writeVt = [&](int buf) {
        int kv = t & 63, d0 = (t >> 6) * 8;
        #pragma unroll
        for (int j = 0; j < 8; ++j) {
            Vt[buf][(d0 + j) * PSTR + kv]      = vva[j];
            Vt[buf][(d0 + 32 + j) * PSTR + kv] = vvb[j];
        }
    };

    stageK(0, 0);
    loadV(0);
    writeVt(0);

    int cur = 0;
    for (int it = 0; it < nt; ++it) {
        const int kv0 = it * 64;
        __syncthreads();

        if (it + 1 < nt) { stageK(cur ^ 1, kv0 + 64); loadV(kv0 + 64); }

        if (kv0 <= qmax) {
            const bool act1 = (kv0 + 32 <= qmax);

            // ---- S^T = K Q^T (lane holds S[kv...][q=ql]) ----
            f32x16 sa[2] = {};
            #pragma unroll
            for (int n = 0; n < 2; ++n) {
                if (n == 1 && !act1) continue;
                const int row = n * 32 + ql;
                const int swz = (row & 7) << 4;
                #pragma unroll
                for (int s = 0; s < 4; ++s) {
                    bf16x8 kf = *(const bf16x8*)((const char*)Ks[cur] + row * 128 +
                                                 (((s << 1 | hi) << 4) ^ swz));
                    sa[n] = mfma32(kf, qf[s], sa[n]);
                }
            }

            // ---- mask + row max (in-register tree + one cross-half shfl) ----
            float mx = NEG;
            #pragma unroll
            for (int n = 0; n < 2; ++n) {
                if (n == 1 && !act1) continue;
                if (kv0 + n * 32 + 31 + 4 * hi > q0 + w * 32) {   // any value masked?
                    #pragma unroll
                    for (int r = 0; r < 16; ++r) {
                        int kvg = kv0 + n * 32 + (r & 3) + 8 * (r >> 2) + 4 * hi;
                        if (kvg > qg) sa[n][r] = NEG;
                    }
                }
                float t8[8];
                #pragma unroll
                for (int r = 0; r < 8; ++r) t8[r] = fmaxf(sa[n][r], sa[n][r + 8]);
                float t4a = fmaxf(t8[0], t8[4]), t4b = fmaxf(t8[1], t8[5]);
                float t4c = fmaxf(t8[2], t8[6]), t4d = fmaxf(t8[3], t8[7]);
                mx = fmaxf(mx, fmaxf(fmaxf(t4a, t4b), fmaxf(t4c, t4d)));
            }
            mx = fmaxf(mx, __shfl_xor(mx, 32));
            const float pmax = mx * C;

            // ---- defer-max rescale (T13, THR=8 in log2 domain) ----
            if (__any(pmax > m + 8.f)) {
                float mn = fmaxf(m, pmax);
                float co = __builtin_exp2f(m - mn);
                m = mn; l *= co;
                #pragma unroll
                for (int dt = 0; dt < 2; ++dt)
                    #pragma unroll
                    for (int r = 0; r < 16; ++r) oa[dt][r] *= co;
            }

            // ---- P = exp2(S*C - m); sum; pack to MFMA-B layout (T12) ----
            float rs = 0.f;
            u32x4 pw[2][2];
            #pragma unroll
            for (int n = 0; n < 2; ++n) {
                if (n == 1 && !act1) continue;
                float pv[16];
                #pragma unroll
                for (int r = 0; r < 16; ++r)
                    pv[r] = __builtin_exp2f(fmaf(sa[n][r], C, -m));
                float s8[8];
                #pragma unroll
                for (int r = 0; r < 8; ++r) s8[r] = pv[r] + pv[r + 8];
                rs += ((s8[0] + s8[4]) + (s8[1] + s8[5])) + ((s8[2] + s8[6]) + (s8[3] + s8[7]));
                #pragma unroll
                for (int s = 0; s < 2; ++s) {
                    u32 u0 = cvtpk_bf16(pv[8 * s + 0], pv[8 * s + 1]);
                    u32 u1 = cvtpk_bf16(pv[8 * s + 2], pv[8 * s + 3]);
                    u32 u2 = cvtpk_bf16(pv[8 * s + 4], pv[8 * s + 5]);
                    u32 u3 = cvtpk_bf16(pv[8 * s + 6], pv[8 * s + 7]);
                    plswap(u0, u2);
                    plswap(u1, u3);
                    pw[n][s] = u32x4{u0, u1, u2, u3};
                }
            }
            rs += __shfl_xor(rs, 32);
            l += rs;

            // ---- O^T += V^T P^T ----
            #pragma unroll
            for (int dt = 0; dt < 2; ++dt) {
                const int vrow = dt * 32 + ql;
                #pragma unroll
                for (int n = 0; n < 2; ++n) {
                    if (n == 1 && !act1) continue;
                    #pragma unroll
                    for (int s = 0; s < 2; ++s) {
                        bf16x8 vf = *(const bf16x8*)&Vt[cur][vrow * PSTR + n * 32 + s * 16 + hi * 8];
                        oa[dt] = mfma32(vf, __builtin_bit_cast(bf16x8, pw[n][s]), oa[dt]);
                    }
                }
            }
        }

        if (it + 1 < nt) writeVt(cur ^ 1);
        cur ^= 1;
    }

    // ---- epilogue: transpose O^T -> O via LDS (reuse Vt), coalesced store ----
    __syncthreads();
    u16* ot = ((u16*)Vt) + w * (32 * PSTR);
    const float inv = fastrcp(l);
    #pragma unroll
    for (int dt = 0; dt < 2; ++dt)
        #pragma unroll
        for (int r = 0; r < 16; ++r) {
            int d = dt * 32 + (r & 3) + 8 * (r >> 2) + 4 * hi;
            ot[ql * PSTR + d] = f2bf_fast(oa[dt][r] * inv);
        }
    const int lq = lane >> 1, half = lane & 1;
    const u16* src = ot + lq * PSTR + half * 32;
    u16* dst = Om + headoff + (size_t)(q0 + w * 32 + lq) * D + half * 32;
    #pragma unroll
    for (int seg = 0; seg < 4; ++seg)
        *(u16x8*)(dst + seg * 8) = *(const u16x8*)(src + seg * 8);
}

extern "C" void kernel_launch(void* const* d_in, const int* in_sizes, int n_in,
                              void* d_out, int out_size, void* d_ws, size_t ws_size,
                              hipStream_t stream)
{
    const float* x  = (const float*)d_in[0];
    const float* Wq = (const float*)d_in[1];
    const float* bq = (const float*)d_in[2];
    const float* Wk = (const float*)d_in[3];
    const float* bk = (const float*)d_in[4];
    const float* Wv = (const float*)d_in[5];
    const float* bv = (const float*)d_in[6];
    const float* Wo = (const float*)d_in[7];
    const float* bo = (const float*)d_in[8];

    constexpr int B = 4, T = 2048, D = 1024;
    constexpr size_t MT = (size_t)B * T;   // 8192

    const size_t NEED = (size_t)88 << 20;
    if (ws_size < NEED) return;

    char* ws = (char*)d_ws;
    u16* xb  = (u16*)(ws);
    u16* Wqb = (u16*)(ws + ((size_t)16 << 20));
    u16* Wkb = (u16*)(ws + ((size_t)18 << 20));
    u16* Wvb = (u16*)(ws + ((size_t)20 << 20));
    u16* Wob = (u16*)(ws + ((size_t)22 << 20));
    u16* Qb  = (u16*)(ws + ((size_t)24 << 20));
    u16* Kb  = (u16*)(ws + ((size_t)40 << 20));
    u16* Vb  = (u16*)(ws + ((size_t)56 << 20));
    u16* Ob  = (u16*)(ws + ((size_t)72 << 20));

    int nx4 = (int)(MT * D / 4);
    cvt_f32_bf16<<<(nx4 + 255) / 256, 256, 0, stream>>>(x, xb, nx4);
    int nw4 = D * D / 4;
    cvt_f32_bf16<<<(nw4 + 255) / 256, 256, 0, stream>>>(Wq, Wqb, nw4);
    cvt_f32_bf16<<<(nw4 + 255) / 256, 256, 0, stream>>>(Wk, Wkb, nw4);
    cvt_f32_bf16<<<(nw4 + 255) / 256, 256, 0, stream>>>(Wv, Wvb, nw4);
    cvt_f32_bf16<<<(nw4 + 255) / 256, 256, 0, stream>>>(Wo, Wob, nw4);

    dim3 gg(D / 128, MT / 128);   // (8, 64)
    gemm_bt<0><<<gg, 256, 0, stream>>>(xb, Wqb, bq, Qb, (int)MT, D, D);
    gemm_bt<0><<<gg, 256, 0, stream>>>(xb, Wkb, bk, Kb, (int)MT, D, D);
    gemm_bt<0><<<gg, 256, 0, stream>>>(xb, Wvb, bv, Vb, (int)MT, D, D);

    attn_fwd<<<dim3(T / 128, B * 16), 256, 0, stream>>>(Qb, Kb, Vb, Ob);

    gemm_bt<1><<<gg, 256, 0, stream>>>(Ob, Wob, bo, d_out, (int)MT, D, D);
}

// Round 4
// 230.265 us; speedup vs baseline: 2.4783x; 1.2068x over previous
//
#include <hip/hip_runtime.h>
#include <hip/hip_bf16.h>

#define DEV __device__ __forceinline__

typedef unsigned short u16;
typedef unsigned int u32;
typedef __attribute__((ext_vector_type(4))) float f32x4;
typedef __attribute__((ext_vector_type(16))) float f32x16;
typedef __attribute__((ext_vector_type(8))) __bf16 bf16x8;
typedef __attribute__((ext_vector_type(8))) u16 u16x8;
typedef __attribute__((ext_vector_type(4))) u16 u16x4;
typedef __attribute__((ext_vector_type(4))) u32 u32x4;

DEV u16 f2bf(float f) {
    u32 u = __builtin_bit_cast(u32, f);
    u32 r = (u + 0x7fffu + ((u >> 16) & 1u)) >> 16;
    return (u16)r;
}

DEV u16 f2bf_fast(float f) {
    u32 u = __builtin_bit_cast(u32, f);
    return (u16)((u + 0x8000u) >> 16);
}

DEV float fastrcp(float x) {
#if __has_builtin(__builtin_amdgcn_rcpf)
    return __builtin_amdgcn_rcpf(x);
#else
    return 1.0f / x;
#endif
}

DEV u32 cvtpk_bf16(float lo, float hi) {
    u32 r;
    asm("v_cvt_pk_bf16_f32 %0, %1, %2" : "=v"(r) : "v"(lo), "v"(hi));
    return r;
}

DEV void plswap(u32& a, u32& b) {
    asm volatile("v_permlane32_swap_b32 %0, %1" : "+v"(a), "+v"(b));
}

DEV void gload_lds16(const void* g, void* l) {
    void* gg = const_cast<void*>(g);
    __builtin_amdgcn_global_load_lds(
        (const __attribute__((address_space(1))) void*)gg,
        (__attribute__((address_space(3))) void*)l,
        16, 0, 0);
}

DEV f32x16 mfma32(bf16x8 a, bf16x8 b, f32x16 c) {
    return __builtin_amdgcn_mfma_f32_32x32x16_bf16(a, b, c, 0, 0, 0);
}

// ---------------- f32 -> bf16 conversion ----------------
__global__ void cvt_f32_bf16(const float* __restrict__ in, u16* __restrict__ out, int n4) {
    int i = blockIdx.x * blockDim.x + threadIdx.x;
    if (i < n4) {
        float4 v = ((const float4*)in)[i];
        u16x4 o;
        o[0] = f2bf(v.x); o[1] = f2bf(v.y); o[2] = f2bf(v.z); o[3] = f2bf(v.w);
        ((u16x4*)out)[i] = o;
    }
}

// ---------------- GEMM: C[M,N] = A[M,K] * B[N,K]^T + bias ----------------
template<int F32OUT>
__global__ __launch_bounds__(256) void gemm_bt(
    const u16* __restrict__ A, const u16* __restrict__ B,
    const float* __restrict__ bias, void* __restrict__ Cv,
    int M, int N, int K)
{
    __shared__ u16 As[128 * 64];
    __shared__ u16 Bs[128 * 64];
    const int t = threadIdx.x;
    const int lane = t & 63;
    const int w = t >> 6;
    const int wm = w >> 1, wn = w & 1;
    const int bm = blockIdx.y * 128, bn = blockIdx.x * 128;
    const int lr = lane & 15;
    const int lg = lane >> 4;

    f32x4 acc[4][4] = {};

    for (int k0 = 0; k0 < K; k0 += 64) {
        #pragma unroll
        for (int i = 0; i < 4; ++i) {
            int off = (t + i * 256) * 16;
            int row = off >> 7;
            int colb = off & 127;
            gload_lds16((const char*)A + ((size_t)(bm + row) * K + k0) * 2 + colb,
                        (char*)As + off);
            gload_lds16((const char*)B + ((size_t)(bn + row) * K + k0) * 2 + colb,
                        (char*)Bs + off);
        }
        __syncthreads();
        #pragma unroll
        for (int kk = 0; kk < 2; ++kk) {
            bf16x8 af[4], bfr[4];
            #pragma unroll
            for (int m = 0; m < 4; ++m)
                af[m] = *(const bf16x8*)&As[(wm * 64 + m * 16 + lr) * 64 + kk * 32 + lg * 8];
            #pragma unroll
            for (int n = 0; n < 4; ++n)
                bfr[n] = *(const bf16x8*)&Bs[(wn * 64 + n * 16 + lr) * 64 + kk * 32 + lg * 8];
            #pragma unroll
            for (int m = 0; m < 4; ++m)
                #pragma unroll
                for (int n = 0; n < 4; ++n)
                    acc[m][n] = __builtin_amdgcn_mfma_f32_16x16x32_bf16(af[m], bfr[n], acc[m][n], 0, 0, 0);
        }
        __syncthreads();
    }

    #pragma unroll
    for (int n = 0; n < 4; ++n) {
        int col = bn + wn * 64 + n * 16 + lr;
        float bv = bias[col];
        #pragma unroll
        for (int m = 0; m < 4; ++m) {
            int row0 = bm + wm * 64 + m * 16 + lg * 4;
            #pragma unroll
            for (int r = 0; r < 4; ++r) {
                float v = acc[m][n][r] + bv;
                size_t idx = (size_t)(row0 + r) * N + col;
                if (F32OUT) ((float*)Cv)[idx] = v;
                else        ((u16*)Cv)[idx] = f2bf(v);
            }
        }
    }
}

// ---------------- causal flash attention, v4: fused complementary q-tile pairs
// Block owns q-tiles (8+xq)*128 and (7-xq)*128 of one head: every block does
// exactly 34 tile-iters of MFMA work (balanced). Both tiles share K/V staging
// and LDS fragment reads. 4 waves x 32 q-rows per tile.
__global__ __launch_bounds__(256, 2) void attn_fwd(
    const u16* __restrict__ Qm, const u16* __restrict__ Km, const u16* __restrict__ Vm,
    u16* __restrict__ Om)
{
    constexpr int T = 2048, D = 1024;
    constexpr float C = 0.18033688f;      // 0.125 * log2(e)
    constexpr int PSTR = 72;
    constexpr float NEG = -3.0e38f;

    __shared__ __align__(16) u16 Ks[2][64 * 64];     // XOR-swizzled K rows
    __shared__ __align__(16) u16 Vt[2][64 * PSTR];   // Vt[d][kv]

    const int t = threadIdx.x, lane = t & 63, w = t >> 6;
    const int ql = lane & 31, hi = lane >> 5;

    // XCD-aware remap: id%8 selects 8-head group (4MB K+V ~ one L2)
    const int id = (int)blockIdx.x;
    const int bh = (id & 7) * 8 + ((id >> 3) >> 3);
    const int xq = 7 - ((id >> 3) & 7);              // heavy-first in dispatch order
    const int b = bh >> 4, h = bh & 15;
    const int q0s[2] = { (8 + xq) * 128, (7 - xq) * 128 };
    const size_t headoff = (size_t)b * T * D + h * 64;
    const int nt = q0s[0] / 64 + 2;

    int qg[2], qmax[2];
    #pragma unroll
    for (int ti = 0; ti < 2; ++ti) {
        qg[ti]   = q0s[ti] + w * 32 + ql;
        qmax[ti] = q0s[ti] + w * 32 + 31;
    }

    // ---- Q fragments for both tiles ----
    bf16x8 qf[2][4];
    #pragma unroll
    for (int ti = 0; ti < 2; ++ti) {
        const u16* qp = Qm + headoff + (size_t)qg[ti] * D + hi * 8;
        #pragma unroll
        for (int s = 0; s < 4; ++s) qf[ti][s] = *(const bf16x8*)(qp + s * 16);
    }

    f32x16 oa[2][2] = {};
    float mreg[2] = { NEG, NEG }, lsum[2] = { 0.f, 0.f };

    // ---- staging state (pointer-increment, no per-iter addr recompute) ----
    const int krow = t >> 3, kslot = t & 7;
    const u16* kCur = Km + headoff + (size_t)krow * D + 8 * (kslot ^ (krow & 7));
    const u16* vCur = Vm + headoff + (size_t)(t & 63) * D + (t >> 6) * 8;
    u16* const kDst[2] = { (u16*)Ks[0] + t * 8, (u16*)Ks[1] + t * 8 };
    const int vld = ((t >> 6) * 8) * PSTR + (t & 63);
    u16x8 vva, vvb;

    auto stageK = [&](int buf) {
        gload_lds16(kCur, kDst[buf]);
        gload_lds16(kCur + 32 * D, kDst[buf] + 256 * 8);
        kCur += 64 * D;
    };
    auto loadV = [&]() {
        vva = *(const u16x8*)vCur;
        vvb = *(const u16x8*)(vCur + 32);
        vCur += 64 * D;
    };
    auto writeVt = [&](int buf) {
        u16* vd = (u16*)Vt[buf] + vld;
        #pragma unroll
        for (int j = 0; j < 8; ++j) {
            vd[j * PSTR]        = vva[j];
            vd[(j + 32) * PSTR] = vvb[j];
        }
    };

    stageK(0);
    loadV();
    writeVt(0);

    int cur = 0;
    for (int it = 0; it < nt; ++it) {
        const int kv0 = it * 64;
        __syncthreads();

        const bool more = (it + 1 < nt);
        if (more) { stageK(cur ^ 1); loadV(); }

        const bool a0  = kv0 <= qmax[0],      a1  = kv0 <= qmax[1];
        const bool a0h = kv0 + 32 <= qmax[0], a1h = kv0 + 32 <= qmax[1];

        // ---- S^T = K Q^T, both tiles share kf reads ----
        f32x16 sa[2][2] = {};
        __builtin_amdgcn_s_setprio(1);
        #pragma unroll
        for (int n = 0; n < 2; ++n) {
            const bool c0 = n ? a0h : a0;
            const bool c1 = n ? a1h : a1;
            if (!(c0 || c1)) continue;
            const int row = n * 32 + ql;
            const int swz = (row & 7) << 4;
            #pragma unroll
            for (int s = 0; s < 4; ++s) {
                bf16x8 kf = *(const bf16x8*)((const char*)Ks[cur] + row * 128 +
                                             ((((s << 1) | hi) << 4) ^ swz));
                if (c0) sa[0][n] = mfma32(kf, qf[0][s], sa[0][n]);
                if (c1) sa[1][n] = mfma32(kf, qf[1][s], sa[1][n]);
            }
        }
        __builtin_amdgcn_s_setprio(0);

        // ---- softmax per tile (independent chains -> ILP) ----
        u32x4 pw[2][2][2];
        #pragma unroll
        for (int ti = 0; ti < 2; ++ti) {
            if (kv0 > qmax[ti]) continue;
            const bool acth = (kv0 + 32 <= qmax[ti]);

            float mx = NEG;
            #pragma unroll
            for (int n = 0; n < 2; ++n) {
                if (n == 1 && !acth) continue;
                if (kv0 + n * 32 + 31 + 4 * hi > q0s[ti] + w * 32) {
                    #pragma unroll
                    for (int r = 0; r < 16; ++r) {
                        int kvg = kv0 + n * 32 + (r & 3) + 8 * (r >> 2) + 4 * hi;
                        if (kvg > qg[ti]) sa[ti][n][r] = NEG;
                    }
                }
                float t8[8];
                #pragma unroll
                for (int r = 0; r < 8; ++r) t8[r] = fmaxf(sa[ti][n][r], sa[ti][n][r + 8]);
                float t4a = fmaxf(t8[0], t8[4]), t4b = fmaxf(t8[1], t8[5]);
                float t4c = fmaxf(t8[2], t8[6]), t4d = fmaxf(t8[3], t8[7]);
                mx = fmaxf(mx, fmaxf(fmaxf(t4a, t4b), fmaxf(t4c, t4d)));
            }
            mx = fmaxf(mx, __shfl_xor(mx, 32));
            const float pmax = mx * C;

            if (__any(pmax > mreg[ti] + 8.f)) {
                float mn = fmaxf(mreg[ti], pmax);
                float co = __builtin_exp2f(mreg[ti] - mn);
                mreg[ti] = mn; lsum[ti] *= co;
                #pragma unroll
                for (int dt = 0; dt < 2; ++dt)
                    #pragma unroll
                    for (int r = 0; r < 16; ++r) oa[ti][dt][r] *= co;
            }

            float rs = 0.f;
            #pragma unroll
            for (int n = 0; n < 2; ++n) {
                if (n == 1 && !acth) continue;
                float pv[16];
                #pragma unroll
                for (int r = 0; r < 16; ++r)
                    pv[r] = __builtin_exp2f(fmaf(sa[ti][n][r], C, -mreg[ti]));
                float s8[8];
                #pragma unroll
                for (int r = 0; r < 8; ++r) s8[r] = pv[r] + pv[r + 8];
                rs += ((s8[0] + s8[4]) + (s8[1] + s8[5])) + ((s8[2] + s8[6]) + (s8[3] + s8[7]));
                #pragma unroll
                for (int s = 0; s < 2; ++s) {
                    u32 u0 = cvtpk_bf16(pv[8 * s + 0], pv[8 * s + 1]);
                    u32 u1 = cvtpk_bf16(pv[8 * s + 2], pv[8 * s + 3]);
                    u32 u2 = cvtpk_bf16(pv[8 * s + 4], pv[8 * s + 5]);
                    u32 u3 = cvtpk_bf16(pv[8 * s + 6], pv[8 * s + 7]);
                    plswap(u0, u2);
                    plswap(u1, u3);
                    pw[ti][n][s] = u32x4{u0, u1, u2, u3};
                }
            }
            rs += __shfl_xor(rs, 32);
            lsum[ti] += rs;
        }

        // ---- O^T += V^T P^T, both tiles share vf reads ----
        __builtin_amdgcn_s_setprio(1);
        #pragma unroll
        for (int dt = 0; dt < 2; ++dt) {
            const int vrow = dt * 32 + ql;
            #pragma unroll
            for (int n = 0; n < 2; ++n) {
                const bool c0 = n ? a0h : a0;
                const bool c1 = n ? a1h : a1;
                if (!(c0 || c1)) continue;
                #pragma unroll
                for (int s = 0; s < 2; ++s) {
                    bf16x8 vf = *(const bf16x8*)&Vt[cur][vrow * PSTR + n * 32 + s * 16 + hi * 8];
                    if (c0) oa[0][dt] = mfma32(vf, __builtin_bit_cast(bf16x8, pw[0][n][s]), oa[0][dt]);
                    if (c1) oa[1][dt] = mfma32(vf, __builtin_bit_cast(bf16x8, pw[1][n][s]), oa[1][dt]);
                }
            }
        }
        __builtin_amdgcn_s_setprio(0);

        if (more) writeVt(cur ^ 1);
        cur ^= 1;
    }

    // ---- epilogue: per-tile transpose via LDS (per-wave region), store ----
    __syncthreads();
    u16* ot = ((u16*)Vt) + w * (32 * PSTR);
    const int lq = lane >> 1, half = lane & 1;
    #pragma unroll
    for (int ti = 0; ti < 2; ++ti) {
        const float inv = fastrcp(lsum[ti]);
        #pragma unroll
        for (int dt = 0; dt < 2; ++dt)
            #pragma unroll
            for (int r = 0; r < 16; ++r) {
                int d = dt * 32 + (r & 3) + 8 * (r >> 2) + 4 * hi;
                ot[ql * PSTR + d] = f2bf_fast(oa[ti][dt][r] * inv);
            }
        const u16* src = ot + lq * PSTR + half * 32;
        u16* dst = Om + headoff + (size_t)(q0s[ti] + w * 32 + lq) * D + half * 32;
        #pragma unroll
        for (int seg = 0; seg < 4; ++seg)
            *(u16x8*)(dst + seg * 8) = *(const u16x8*)(src + seg * 8);
    }
}

extern "C" void kernel_launch(void* const* d_in, const int* in_sizes, int n_in,
                              void* d_out, int out_size, void* d_ws, size_t ws_size,
                              hipStream_t stream)
{
    const float* x  = (const float*)d_in[0];
    const float* Wq = (const float*)d_in[1];
    const float* bq = (const float*)d_in[2];
    const float* Wk = (const float*)d_in[3];
    const float* bk = (const float*)d_in[4];
    const float* Wv = (const float*)d_in[5];
    const float* bv = (const float*)d_in[6];
    const float* Wo = (const float*)d_in[7];
    const float* bo = (const float*)d_in[8];

    constexpr int B = 4, T = 2048, D = 1024;
    constexpr size_t MT = (size_t)B * T;   // 8192

    const size_t NEED = (size_t)88 << 20;
    if (ws_size < NEED) return;

    char* ws = (char*)d_ws;
    u16* xb  = (u16*)(ws);
    u16* Wqb = (u16*)(ws + ((size_t)16 << 20));
    u16* Wkb = (u16*)(ws + ((size_t)18 << 20));
    u16* Wvb = (u16*)(ws + ((size_t)20 << 20));
    u16* Wob = (u16*)(ws + ((size_t)22 << 20));
    u16* Qb  = (u16*)(ws + ((size_t)24 << 20));
    u16* Kb  = (u16*)(ws + ((size_t)40 << 20));
    u16* Vb  = (u16*)(ws + ((size_t)56 << 20));
    u16* Ob  = (u16*)(ws + ((size_t)72 << 20));

    int nx4 = (int)(MT * D / 4);
    cvt_f32_bf16<<<(nx4 + 255) / 256, 256, 0, stream>>>(x, xb, nx4);
    int nw4 = D * D / 4;
    cvt_f32_bf16<<<(nw4 + 255) / 256, 256, 0, stream>>>(Wq, Wqb, nw4);
    cvt_f32_bf16<<<(nw4 + 255) / 256, 256, 0, stream>>>(Wk, Wkb, nw4);
    cvt_f32_bf16<<<(nw4 + 255) / 256, 256, 0, stream>>>(Wv, Wvb, nw4);
    cvt_f32_bf16<<<(nw4 + 255) / 256, 256, 0, stream>>>(Wo, Wob, nw4);

    dim3 gg(D / 128, MT / 128);   // (8, 64)
    gemm_bt<0><<<gg, 256, 0, stream>>>(xb, Wqb, bq, Qb, (int)MT, D, D);
    gemm_bt<0><<<gg, 256, 0, stream>>>(xb, Wkb, bk, Kb, (int)MT, D, D);
    gemm_bt<0><<<gg, 256, 0, stream>>>(xb, Wvb, bv, Vb, (int)MT, D, D);

    attn_fwd<<<dim3(512), 256, 0, stream>>>(Qb, Kb, Vb, Ob);

    gemm_bt<1><<<gg, 256, 0, stream>>>(Ob, Wob, bo, d_out, (int)MT, D, D);
}